// Round 1
// baseline (3103.190 us; speedup 1.0000x reference)
//
#include <hip/hip_runtime.h>
#include <hip/hip_bf16.h>
#include <stdint.h>

// NeuralFSDE: 1000 sequential steps of x += mlp_d(x)*dt + mlp_s(x)*(fgn*dt^H)
// B=128, S=256, Hd=512. Weight-stationary design:
//   32 clusters x 8 wgs; cluster owns 4 batch rows for all steps.
//   wg j holds a 128-wide hidden slice of (drift|diff) MLP in REGISTERS
//   (bf16 MFMA fragments), computes partial y, exchanges partials via
//   system-scope (sc0 sc1) stores/loads + flag sync each step.
//   x state lives in fp32 registers (4 floats/thread); only the MFMA input
//   copy is rounded to bf16 each step.

typedef __attribute__((ext_vector_type(8))) short bf16x8;
typedef __attribute__((ext_vector_type(4))) float f32x4;
typedef __attribute__((ext_vector_type(4))) unsigned short u16x4;

#define MFMA16(a, b, c) __builtin_amdgcn_mfma_f32_16x16x32_bf16((a), (b), (c), 0, 0, 0)

__device__ __forceinline__ unsigned short f2bf(float f) {
  union { float f; uint32_t u; } v; v.f = f;
  return (unsigned short)((v.u + 0x7fffu + ((v.u >> 16) & 1u)) >> 16);
}

__device__ __forceinline__ float fast_tanh(float z) {
  float az = __builtin_fabsf(z);
  float e = __expf(-2.0f * az);
  float r = (1.0f - e) * __builtin_amdgcn_rcpf(1.0f + e);
  return z < 0.0f ? -r : r;
}

// system-scope write-through store (visible device-wide after vmcnt ack)
__device__ __forceinline__ void store_wt_f(float* p, float v) {
  asm volatile("global_store_dword %0, %1, off sc0 sc1" :: "v"(p), "v"(v) : "memory");
}
__device__ __forceinline__ void store_wt_i(int* p, int v) {
  asm volatile("global_store_dword %0, %1, off sc0 sc1" :: "v"(p), "v"(v) : "memory");
}
__device__ __forceinline__ int load_wt_i(const int* p) {
  int v;
  asm volatile("global_load_dword %0, %1, off sc0 sc1\n\ts_waitcnt vmcnt(0)"
               : "=&v"(v) : "v"(p) : "memory");
  return v;
}

__global__ __launch_bounds__(256, 1) void fsde_kernel(
    const float* __restrict__ x0,
    const float* __restrict__ Wd1, const float* __restrict__ bd1,
    const float* __restrict__ Wd2, const float* __restrict__ bd2,
    const float* __restrict__ Ws1, const float* __restrict__ bs1,
    const float* __restrict__ Ws2, const float* __restrict__ bs2,
    const float* __restrict__ rawh,
    const float* __restrict__ fgn,
    const int* __restrict__ nsp,
    float* __restrict__ out,
    float* __restrict__ part,   // [2][32][8][4][256] fp32 partials (2 MB)
    int* __restrict__ flags)    // [32][8], memset to 0 before launch
{
  // LDS: all < 64 KB static. Row strides padded so stride % 32 dwords == 4
  // -> 16-lane MFMA frag reads are 2-way bank aliased (free, m136) and rows
  // stay 16B aligned for ds_read_b128.
  __shared__ __align__(16) unsigned short Xs[16 * 264];   // x tile, bf16
  __shared__ __align__(16) unsigned short Hs[16 * 136];   // hidden tile, bf16
  __shared__ __align__(16) unsigned short STG[8704];      // weight staging scratch
  __shared__ float B1[128];

  const int tid = threadIdx.x;
  const int lane = tid & 63;
  const int wv = tid >> 6;   // wave 0..3
  const int q = lane >> 4;   // quad 0..3
  const int cl = lane & 15;

  // block -> (cluster c, shard j); cluster's 8 blocks share bid%8 (same XCD
  // under round-robin dispatch -- perf heuristic only, correctness does not
  // depend on it: all cross-wg traffic is system-scope).
  const int bid = blockIdx.x;
  const int c = (bid & 7) * 4 + ((bid >> 3) >> 3);  // 0..31
  const int j = (bid >> 3) & 7;                     // 0..7

  const int NS = nsp[0];
  const float dt = 1.0f / (float)NS;  // T_MAX = 1.0
  const float Hh = 0.98f / (1.0f + expf(-rawh[0])) + 0.01f;
  const float nsc = expf(Hh * logf(dt));  // dt^H

  const float* W1g = (j < 4) ? Wd1 : Ws1;  // [256][512]
  const float* W2g = (j < 4) ? Wd2 : Ws2;  // [512][256]
  const float* b1g = (j < 4) ? bd1 : bs1;
  const int jj = (j & 3) * 128;  // hidden slice start

  // ---- stage layer-1 weight frags into registers (per-wave 32-col chunks) ----
  // w1f[i][kt]: B-operand frag, n = (wv*2+i)*16+cl (local), k = kt*32+q*8..+7
  bf16x8 w1f[2][8];
  for (int wc = 0; wc < 4; ++wc) {
    __syncthreads();
    for (int idx = tid; idx < 32 * 256; idx += 256) {
      int n = idx & 31, k = idx >> 5;
      STG[n * 264 + k] = f2bf(W1g[k * 512 + jj + wc * 32 + n]);
    }
    __syncthreads();
    if (wv == wc) {
#pragma unroll
      for (int i = 0; i < 2; ++i)
#pragma unroll
        for (int kt = 0; kt < 8; ++kt)
          w1f[i][kt] = *(const bf16x8*)&STG[(i * 16 + cl) * 264 + kt * 32 + q * 8];
    }
  }
  // ---- stage layer-2 weight frags (per-wave 64-col chunks) ----
  bf16x8 w2f[4][4];
  for (int wc = 0; wc < 4; ++wc) {
    __syncthreads();
    for (int idx = tid; idx < 64 * 128; idx += 256) {
      int n = idx & 63, k = idx >> 6;
      STG[n * 136 + k] = f2bf(W2g[(jj + k) * 256 + wc * 64 + n]);
    }
    __syncthreads();
    if (wv == wc) {
#pragma unroll
      for (int i = 0; i < 4; ++i)
#pragma unroll
        for (int kt = 0; kt < 4; ++kt)
          w2f[i][kt] = *(const bf16x8*)&STG[(i * 16 + cl) * 136 + kt * 32 + q * 8];
    }
  }

  if (tid < 128) B1[tid] = b1g[jj + tid];
  // zero x pad rows 4..15 (kept zero forever; updates touch rows 0..3 only)
  for (int idx = tid; idx < 12 * 264; idx += 256) Xs[4 * 264 + idx] = 0;

  // ---- per-thread state mapping: thread -> (row ub, cols us..us+3) ----
  const int ub = tid >> 6;
  const int us4 = tid & 63;
  const int us = us4 * 4;
  const int grow = 4 * c + ub;  // global batch row

  f32x4 xr = *(const f32x4*)(x0 + grow * 256 + us);  // fp32 master state
  f32x4 b2d = *(const f32x4*)(bd2 + us);
  f32x4 b2s = *(const f32x4*)(bs2 + us);

  {
    u16x4 xu;
#pragma unroll
    for (int i2 = 0; i2 < 4; ++i2) xu[i2] = f2bf(xr[i2]);
    *(u16x4*)&Xs[ub * 264 + us] = xu;
  }
  float* trow = out + (size_t)grow * (size_t)(NS + 1) * 256 + us;
  if (j == 0) *(f32x4*)trow = xr;  // trajectory slot 0 = x0

  __syncthreads();

  for (int t = 0; t < NS; ++t) {
    // prefetch this step's noise early (hidden behind GEMMs)
    f32x4 nf = *(const f32x4*)(fgn + ((size_t)t * 128 + grow) * 256 + us);

    // ---- GEMM1: h_pre[16,32(wave)] = x[16,256] @ W1slice ----
    f32x4 acc0 = {0.f, 0.f, 0.f, 0.f}, acc1 = {0.f, 0.f, 0.f, 0.f};
#pragma unroll
    for (int kt = 0; kt < 8; ++kt) {
      bf16x8 a = *(const bf16x8*)&Xs[cl * 264 + kt * 32 + q * 8];
      acc0 = MFMA16(a, w1f[0][kt], acc0);
      acc1 = MFMA16(a, w1f[1][kt], acc1);
    }
    // bias + tanh -> Hs (bf16), C-layout: row=q*4+r, col=tile*16+cl
#pragma unroll
    for (int i = 0; i < 2; ++i) {
      int col = (wv * 2 + i) * 16 + cl;
      float bb = B1[col];
      f32x4 v = i ? acc1 : acc0;
#pragma unroll
      for (int r = 0; r < 4; ++r)
        Hs[(q * 4 + r) * 136 + col] = f2bf(fast_tanh(v[r] + bb));
    }
    __syncthreads();

    // ---- GEMM2: partial[16,64(wave)] = h[16,128] @ W2slice ----
    f32x4 pacc[4] = {{0.f,0.f,0.f,0.f},{0.f,0.f,0.f,0.f},{0.f,0.f,0.f,0.f},{0.f,0.f,0.f,0.f}};
#pragma unroll
    for (int kt = 0; kt < 4; ++kt) {
      bf16x8 a = *(const bf16x8*)&Hs[cl * 136 + kt * 32 + q * 8];
#pragma unroll
      for (int i = 0; i < 4; ++i) pacc[i] = MFMA16(a, w2f[i][kt], pacc[i]);
    }

    // ---- publish partial rows 0..3 (live in lanes q==0, regs r=0..3) ----
    float* pbase = part + ((size_t)((t & 1) * 32 + c) * 8 + j) * 1024;
    if (q == 0) {
#pragma unroll
      for (int i = 0; i < 4; ++i) {
        int col = (wv * 4 + i) * 16 + cl;
#pragma unroll
        for (int r = 0; r < 4; ++r) store_wt_f(pbase + r * 256 + col, pacc[i][r]);
      }
    }
    asm volatile("s_waitcnt vmcnt(0)" ::: "memory");  // drain own WT stores
    __syncthreads();
    if (tid == 0) store_wt_i(flags + c * 8 + j, t + 1);
    if (tid < 8) {
      const int* fp = flags + c * 8 + tid;
      while (load_wt_i(fp) < t + 1) {}
    }
    __syncthreads();

    // ---- gather all 8 partials (system-scope, bypass caches) ----
    f32x4 p0, p1, p2, p3, p4, p5, p6, p7;
    {
      const uint32_t voff = (uint32_t)(ub * 1024 + us4 * 16);  // byte offset
      const float* gb = part + ((size_t)((t & 1) * 32 + c) * 8) * 1024;
      asm volatile(
          "global_load_dwordx4 %0, %8, %9 sc0 sc1\n\t"
          "global_load_dwordx4 %1, %8, %10 sc0 sc1\n\t"
          "global_load_dwordx4 %2, %8, %11 sc0 sc1\n\t"
          "global_load_dwordx4 %3, %8, %12 sc0 sc1\n\t"
          "global_load_dwordx4 %4, %8, %13 sc0 sc1\n\t"
          "global_load_dwordx4 %5, %8, %14 sc0 sc1\n\t"
          "global_load_dwordx4 %6, %8, %15 sc0 sc1\n\t"
          "global_load_dwordx4 %7, %8, %16 sc0 sc1\n\t"
          "s_waitcnt vmcnt(0)"
          : "=&v"(p0), "=&v"(p1), "=&v"(p2), "=&v"(p3),
            "=&v"(p4), "=&v"(p5), "=&v"(p6), "=&v"(p7)
          : "v"(voff),
            "s"(gb), "s"(gb + 1024), "s"(gb + 2048), "s"(gb + 3072),
            "s"(gb + 4096), "s"(gb + 5120), "s"(gb + 6144), "s"(gb + 7168)
          : "memory");
    }
    f32x4 dsum = p0 + p1 + p2 + p3;
    f32x4 ssum = p4 + p5 + p6 + p7;
#pragma unroll
    for (int i2 = 0; i2 < 4; ++i2)
      xr[i2] += (dsum[i2] + b2d[i2]) * dt + (ssum[i2] + b2s[i2]) * (nf[i2] * nsc);

    {
      u16x4 xu;
#pragma unroll
      for (int i2 = 0; i2 < 4; ++i2) xu[i2] = f2bf(xr[i2]);
      *(u16x4*)&Xs[ub * 264 + us] = xu;
    }
    if (j == 0) *(f32x4*)(trow + (size_t)(t + 1) * 256) = xr;
    __syncthreads();
  }
}

extern "C" void kernel_launch(void* const* d_in, const int* in_sizes, int n_in,
                              void* d_out, int out_size, void* d_ws, size_t ws_size,
                              hipStream_t stream) {
  const float* x0  = (const float*)d_in[0];
  const float* Wd1 = (const float*)d_in[1];
  const float* bd1 = (const float*)d_in[2];
  const float* Wd2 = (const float*)d_in[3];
  const float* bd2 = (const float*)d_in[4];
  const float* Ws1 = (const float*)d_in[5];
  const float* bs1 = (const float*)d_in[6];
  const float* Ws2 = (const float*)d_in[7];
  const float* bs2 = (const float*)d_in[8];
  const float* rawh = (const float*)d_in[9];
  const float* fgn = (const float*)d_in[10];
  const int* nsp = (const int*)d_in[11];
  float* out = (float*)d_out;

  float* part = (float*)d_ws;                                   // 2 MB
  int* flags = (int*)((char*)d_ws + (size_t)(2 * 1024 * 1024)); // 1 KB

  // flags must start at 0 every launch (ws is re-poisoned to 0xAA)
  hipMemsetAsync(flags, 0, 32 * 8 * sizeof(int), stream);

  fsde_kernel<<<dim3(256), dim3(256), 0, stream>>>(
      x0, Wd1, bd1, Wd2, bd2, Ws1, bs1, Ws2, bs2, rawh, fgn, nsp, out, part, flags);
}